// Round 2
// baseline (47.968 us; speedup 1.0000x reference)
//
#include <hip/hip_runtime.h>
#include <math.h>

#define HDIM 2048
#define NEXP 8
#define TB 8                       // tokens per wave
#define WPB 4                      // waves per block
#define TPB (TB * WPB)             // tokens per block = 32

// ---------------------------------------------------------------------------
// One wave handles TB=8 tokens. Lanes split H (float4 each, 256 floats/wave
// per iter); each lane accumulates partials for all 64 (token,expert) pairs,
// then a 6-step shuffle fold leaves lane l holding logit(token l>>3,
// expert l&7). Top-2 + softmax in-register; histogram via LDS + one float
// atomic per (block, expert).
// ---------------------------------------------------------------------------
__global__ __launch_bounds__(256) void
router_main(const float* __restrict__ x,
            const float* __restrict__ W,
            float* __restrict__ out_scores,   // [T,2]
            float* __restrict__ out_idx,      // [T,2] as float
            float* __restrict__ hist,         // [8], pre-zeroed
            int T)
{
    __shared__ int cnt[NEXP];
    if (threadIdx.x < NEXP) cnt[threadIdx.x] = 0;
    __syncthreads();

    const int lane = threadIdx.x & 63;
    const int wv   = threadIdx.x >> 6;
    const int tok0 = (blockIdx.x * WPB + wv) * TB;

    // per-token base pointers (statically indexed -> registers)
    const float* xb[TB];
#pragma unroll
    for (int t = 0; t < TB; ++t) {
        int tt = tok0 + t; if (tt > T - 1) tt = T - 1;   // in-bounds clamp
        xb[t] = x + (size_t)tt * HDIM + lane * 4;
    }
    const float* wb = W + lane * 4;

    float acc[TB * NEXP];
#pragma unroll
    for (int i = 0; i < TB * NEXP; ++i) acc[i] = 0.f;

#pragma unroll
    for (int iter = 0; iter < HDIM / 256; ++iter) {
        const int h = iter * 256;
        float4 xv[TB];
#pragma unroll
        for (int t = 0; t < TB; ++t)
            xv[t] = *reinterpret_cast<const float4*>(xb[t] + h);
        float4 w[NEXP];
#pragma unroll
        for (int e = 0; e < NEXP; ++e)
            w[e] = *reinterpret_cast<const float4*>(wb + (size_t)e * HDIM + h);
#pragma unroll
        for (int t = 0; t < TB; ++t) {
#pragma unroll
            for (int e = 0; e < NEXP; ++e) {
                float a = acc[t * NEXP + e];
                a = fmaf(xv[t].x, w[e].x, a);
                a = fmaf(xv[t].y, w[e].y, a);
                a = fmaf(xv[t].z, w[e].z, a);
                a = fmaf(xv[t].w, w[e].w, a);
                acc[t * NEXP + e] = a;
            }
        }
    }

    // ---- fold 64 partial sums across 64 lanes (all static indices) ----
#define FOLD(SM)                                                          \
    {                                                                     \
        const bool up = (lane & SM) != 0;                                 \
        _Pragma("unroll")                                                 \
        for (int j = 0; j < SM; ++j) {                                    \
            float keep = up ? acc[j + SM] : acc[j];                       \
            float send = up ? acc[j] : acc[j + SM];                       \
            acc[j] = keep + __shfl_xor(send, SM, 64);                     \
        }                                                                 \
    }
    FOLD(32) FOLD(16) FOLD(8) FOLD(4) FOLD(2) FOLD(1)
#undef FOLD

    // lane l holds logit(token tok0 + (l>>3), expert l&7)
    const int e_my  = lane & 7;
    const int t_loc = lane >> 3;
    const float mylg = acc[0];

    // ---- top-1 within each aligned 8-lane group (tie -> lower index) ----
    float v1 = mylg;
    int   i1 = e_my;
#pragma unroll
    for (int m = 1; m <= 4; m <<= 1) {
        float ov = __shfl_xor(v1, m, 64);
        int   oi = __shfl_xor(i1, m, 64);
        if (ov > v1 || (ov == v1 && oi < i1)) { v1 = ov; i1 = oi; }
    }
    // ---- top-2: exclude i1, repeat ----
    float v2 = (e_my == i1) ? -3.402823466e+38f : mylg;
    int   i2 = e_my;
#pragma unroll
    for (int m = 1; m <= 4; m <<= 1) {
        float ov = __shfl_xor(v2, m, 64);
        int   oi = __shfl_xor(i2, m, 64);
        if (ov > v2 || (ov == v2 && oi < i2)) { v2 = ov; i2 = oi; }
    }

    // ---- softmax over the 2 selected logits (fp32, stable: v1 >= v2) ----
    const float ed  = expf(v2 - v1);
    const float inv = 1.0f / (1.0f + ed);

    const int tok = tok0 + t_loc;
    if (e_my == 0 && tok < T) {
        *reinterpret_cast<float2*>(out_scores + 2 * tok) = make_float2(inv, ed * inv);
        *reinterpret_cast<float2*>(out_idx   + 2 * tok) = make_float2((float)i1, (float)i2);
        atomicAdd(&cnt[i1], 1);
        atomicAdd(&cnt[i2], 1);
    }

    __syncthreads();
    // integer-valued float adds are exact (< 2^24) -> order-independent,
    // deterministic. 512 atomics per expert address, spread over the kernel.
    if (threadIdx.x < NEXP)
        atomicAdd(&hist[threadIdx.x], (float)cnt[threadIdx.x]);
}

extern "C" void kernel_launch(void* const* d_in, const int* in_sizes, int n_in,
                              void* d_out, int out_size, void* d_ws, size_t ws_size,
                              hipStream_t stream)
{
    const float* x = (const float*)d_in[0];
    const float* W = (const float*)d_in[1];
    const int T = in_sizes[0] / HDIM;          // 16384

    float* out        = (float*)d_out;
    float* out_scores = out;                   // [T,2]
    float* out_idx    = out + (size_t)2 * T;   // [T,2]
    float* hist       = out + (size_t)4 * T;   // [8]

    // zero the 8 hist slots every call (atomics accumulate into them)
    hipMemsetAsync(hist, 0, NEXP * sizeof(float), stream);

    const int nblocks = (T + TPB - 1) / TPB;   // 512
    router_main<<<nblocks, 256, 0, stream>>>(x, W, out_scores, out_idx, hist, T);
}